// Round 1
// 429.745 us; speedup vs baseline: 1.0018x; 1.0018x over previous
//
#include <hip/hip_runtime.h>

// out[n, d] = in[n, d] * W[d]   (N=16384, D=4096, fp32)
// Memory-bound streaming: 537 MB total HBM traffic -> roofline ~85 us at 6.3 TB/s.
// Counters showed the 430 us bench window = ~332 us harness re-poison fills
// (2x 1 GiB fillBuffer @ 6.4 TB/s, untouchable) + ~98 us kernel.
// This version targets the kernel's gap to the wall:
//  - nontemporal (nt) load/store: zero-reuse stream, don't thrash 32 MB L2
//  - W4 load hoisted: grid stride (8192*256 = 2,097,152) is a multiple of
//    D/4 = 1024, so (i & 1023) is loop-invariant -> one W load per thread
//  - x2 unroll: 2 outstanding 16 B loads per thread per loop body

typedef float v4f __attribute__((ext_vector_type(4)));

__global__ __launch_bounds__(256) void Diag_14285061227129_kernel(
        const v4f* __restrict__ in,
        const v4f* __restrict__ W4,
        v4f* __restrict__ out,
        long long n4) {
    const long long stride = (long long)gridDim.x * blockDim.x;  // 2,097,152
    long long i = (long long)blockIdx.x * blockDim.x + threadIdx.x;

    // stride % 1024 == 0  ->  W index is invariant across grid-stride iters.
    const v4f w = W4[i & 1023];   // 16 KiB table, L1-resident

    // n4 / stride == 8 exactly for the default launch; keep the guarded
    // tail for robustness to other shapes.
    for (; i + stride < n4; i += 2 * stride) {
        v4f v0 = __builtin_nontemporal_load(&in[i]);
        v4f v1 = __builtin_nontemporal_load(&in[i + stride]);
        v0 *= w;
        v1 *= w;
        __builtin_nontemporal_store(v0, &out[i]);
        __builtin_nontemporal_store(v1, &out[i + stride]);
    }
    if (i < n4) {
        v4f v = __builtin_nontemporal_load(&in[i]);
        v *= w;
        __builtin_nontemporal_store(v, &out[i]);
    }
}

extern "C" void kernel_launch(void* const* d_in, const int* in_sizes, int n_in,
                              void* d_out, int out_size, void* d_ws, size_t ws_size,
                              hipStream_t stream) {
    const v4f* in = (const v4f*)d_in[0];
    const v4f* W4 = (const v4f*)d_in[1];
    v4f* out = (v4f*)d_out;

    const long long n4 = (long long)out_size / 4;  // 67,108,864 / 4 = 16,777,216

    // 8192 blocks x 256 threads = 2,097,152 threads -> 8 float4 iters each
    // (4 unrolled-x2 loop bodies). Stride stays a multiple of 1024 so the
    // hoisted-W trick holds.
    const int block = 256;
    const int grid = 8192;
    Diag_14285061227129_kernel<<<grid, block, 0, stream>>>(in, W4, out, n4);
}